// Round 1
// 868.938 us; speedup vs baseline: 1.0914x; 1.0914x over previous
//
#include <hip/hip_runtime.h>
#include <hip/hip_bf16.h>

typedef unsigned short u16;
typedef unsigned int   u32;
typedef unsigned long long u64;
typedef __attribute__((ext_vector_type(4)))  float  f32x4;
typedef __attribute__((ext_vector_type(8)))  short  short8;
typedef __attribute__((ext_vector_type(16))) float  f32x16;

#define MB     256
#define SRCT   120
#define DECT   24
#define NSTEP  144
#define DIN    216
#define HDIM   1024
#define KXP    224
#define KA     1248
#define NGATE  4096
#define OUTD   216
#define NWG    256

// ---- ws layout (bytes) ---- (unchanged from previous version)
#define OFF_SRCBF 0u
#define OFF_H     13762560u
#define OFF_XDEC  14811136u
#define OFF_WCAT  14925824u
#define OFF_WO    25149440u
#define OFF_BAR   25591808u      // 8 groups x 64 u32 (accumulating counters)

__device__ __forceinline__ u16 f2bf(float f) {
    union { float f; unsigned v; } c; c.f = f;
    return (u16)((c.v + 0x7FFFu + ((c.v >> 16) & 1u)) >> 16);
}
__device__ __forceinline__ float sigm(float x)  { return 1.0f / (1.0f + __expf(-x)); }
__device__ __forceinline__ float tanh_(float x) { return 1.0f - 2.0f / (1.0f + __expf(2.0f * x)); }

__device__ __forceinline__ void astore(u64* p, u64 v) {
    __hip_atomic_store(p, v, __ATOMIC_RELAXED, __HIP_MEMORY_SCOPE_AGENT);
}

// coherent 16B global->VGPR load (reads through the device coherence point).
// Issued async; consumer must vwait<> before reading the result.
__device__ __forceinline__ short8 ld_sc(const u16* p) {
    short8 r;
    asm volatile("global_load_dwordx4 %0, %1, off sc0 sc1" : "=v"(r) : "v"(p));
    return r;
}
template <int N>
__device__ __forceinline__ void vwait() {
    asm volatile("s_waitcnt vmcnt(%0)" :: "n"(N));
    __builtin_amdgcn_sched_barrier(0);   // keep MFMAs from hoisting above the wait
}

// ---- single-counter group barrier: 1 atomicAdd / WG, 1 polling lane ----
// slots accumulate monotonically; slot (k&63), generation target 32*((k>>6)+1).
__device__ __forceinline__ void g_arrive(u32* slots, int k) {
    __syncthreads();   // drains all waves' stores (vmcnt 0) before the flag
    if (threadIdx.x == 0)
        __hip_atomic_fetch_add(slots + (k & 63), 1u, __ATOMIC_RELAXED, __HIP_MEMORY_SCOPE_AGENT);
}
__device__ __forceinline__ void g_wait(u32* slots, int k) {
    if (threadIdx.x == 0) {
        const u32 tgt = 32u * (u32)((k >> 6) + 1);
        while (__hip_atomic_load(slots + (k & 63), __ATOMIC_RELAXED, __HIP_MEMORY_SCOPE_AGENT) < tgt)
            __builtin_amdgcn_s_sleep(1);
    }
    __syncthreads();
}

// ---------------- prep: fp32 -> bf16, transposed comm layouts ----------------
__global__ void prep_kernel(const float* __restrict__ src,
                            const float* __restrict__ W_ih,
                            const float* __restrict__ W_hh,
                            const float* __restrict__ W_out,
                            u16* __restrict__ srcbf, u16* __restrict__ H,
                            u16* __restrict__ Xd,    u16* __restrict__ Wcat,
                            u16* __restrict__ Wo,    u32* __restrict__ bar) {
    const int nS  = SRCT * 8 * 28 * 256;
    const int nW  = NGATE * KA;
    const int nWo = OUTD * HDIM;
    const int nH  = MB * HDIM;
    const int nXd = 8 * 28 * 256;
    const int nB  = 8 * 64;
    const int total = nS + nW + nWo + nH + nXd + nB;
    for (int i = blockIdx.x * blockDim.x + threadIdx.x; i < total; i += gridDim.x * blockDim.x) {
        if (i < nS) {
            int r = i & 255, i2 = i >> 8;
            int m = r >> 3, e = r & 7;
            int oct = i2 % 28, q = i2 / 28;
            int gi = q & 7, t = q >> 3;
            int col = oct * 8 + e, b = gi * 32 + m;
            srcbf[i] = (col < DIN) ? f2bf(src[((size_t)b * SRCT + t) * DIN + col]) : (u16)0;
        } else if (i < nS + nW) {
            int j = i - nS;
            int r = j / KA, col = j % KA;
            u16 v = 0;
            if (col < DIN)       v = f2bf(W_ih[(size_t)r * DIN + col]);
            else if (col >= KXP) v = f2bf(W_hh[(size_t)r * HDIM + (col - KXP)]);
            Wcat[j] = v;
        } else if (i < nS + nW + nWo) {
            int j = i - nS - nW;
            Wo[j] = f2bf(W_out[j]);
        } else if (i < nS + nW + nWo + nH) {
            H[i - nS - nW - nWo] = 0;
        } else if (i < nS + nW + nWo + nH + nXd) {
            Xd[i - nS - nW - nWo - nH] = 0;
        } else {
            bar[i - nS - nW - nWo - nH - nXd] = 0;
        }
    }
}

// ---------------- gate GEMM: direct-load A-fragment pipeline ----------------
// tile J: kt = ktb+J (clamped to 77); even-oct o2=2*kt; A addr = base + kg*256 + l31*8
template <int J>
__device__ __forceinline__ void gate_issue(short8 (&av)[20], const u16* xb, const u16* hb,
                                           int ktb, int lo) {
    int kt = ktb + J;
    if (kt > 77) kt = 77;                       // pad tile: valid addr, B is zeroed
    const int o2 = 2 * kt;
    const u16* base = (o2 < 28) ? (xb + o2 * 256) : (hb + (o2 - 28) * 256);
    av[J] = ld_sc(base + lo);
}
template <int J>
__device__ __forceinline__ void gate_pro(short8 (&av)[20], const u16* xb, const u16* hb,
                                         int ktb, int lo) {
    gate_issue<J>(av, xb, hb, ktb, lo);
    if constexpr (J + 1 < 8) gate_pro<J + 1>(av, xb, hb, ktb, lo);
}
template <int J>
__device__ __forceinline__ void gate_body(short8 (&av)[20], short8 (&Bf)[4][20], f32x16 (&acc)[4],
                                          const u16* xb, const u16* hb, int ktb, int lo) {
    if constexpr (J + 8 < 20) gate_issue<J + 8>(av, xb, hb, ktb, lo);
    vwait<(J + 8 < 20) ? 8 : (19 - J)>();
    acc[0] = __builtin_amdgcn_mfma_f32_32x32x16_bf16(av[J], Bf[0][J], acc[0], 0, 0, 0);
    acc[1] = __builtin_amdgcn_mfma_f32_32x32x16_bf16(av[J], Bf[1][J], acc[1], 0, 0, 0);
    acc[2] = __builtin_amdgcn_mfma_f32_32x32x16_bf16(av[J], Bf[2][J], acc[2], 0, 0, 0);
    acc[3] = __builtin_amdgcn_mfma_f32_32x32x16_bf16(av[J], Bf[3][J], acc[3], 0, 0, 0);
    if constexpr (J + 1 < 20) gate_body<J + 1>(av, Bf, acc, xb, hb, ktb, lo);
}

// ---------------- out GEMM: direct-load A (h_new), B from Wo ----------------
template <int J>
__device__ __forceinline__ void out_issue(short8 (&av)[16], const u16* hb, int kt0, int lo) {
    const int o2 = 2 * (kt0 + J);
    av[J] = ld_sc(hb + o2 * 256 + lo);
}
template <int J>
__device__ __forceinline__ void out_pro(short8 (&av)[16], const u16* hb, int kt0, int lo) {
    out_issue<J>(av, hb, kt0, lo);
    if constexpr (J + 1 < 8) out_pro<J + 1>(av, hb, kt0, lo);
}
template <int J>
__device__ __forceinline__ void out_body(short8 (&av)[16], f32x16& oacc, const u16* hb,
                                         const u16* wob, int kt0, int lo) {
    if constexpr (J + 8 < 16) out_issue<J + 8>(av, hb, kt0, lo);
    vwait<(J + 8 < 16) ? 8 : (15 - J)>();
    short8 bf = *(const short8*)(wob + (size_t)(kt0 + J) * 16);
    oacc = __builtin_amdgcn_mfma_f32_32x32x16_bf16(av[J], bf, oacc, 0, 0, 0);
    if constexpr (J + 1 < 16) out_body<J + 1>(av, oacc, hb, wob, kt0, lo);
}

// ---------------- persistent LSTM ----------------
// group g = bid&7: batches [g*32,+32). slice s = bid>>3: h-cols [s*32,+32) x 4 gates.
// Waves K-split; B pinned in regs; A-fragments direct-loaded from IC (no LDS staging).
__global__ void __launch_bounds__(256, 1)
lstm_persist(const u16* __restrict__ srcbf, u16* __restrict__ H,
             u16* __restrict__ Xd, const u16* __restrict__ Wcat,
             const u16* __restrict__ Wo,
             const float* __restrict__ b_ih, const float* __restrict__ b_hh,
             const float* __restrict__ b_out,
             float* __restrict__ dout, u32* __restrict__ bar)
{
    __shared__ __align__(16) float G2[16 * 32 * 36];   // [slab][col][b36] 73,728 B
    __shared__ __align__(16) u16  Hx[4 * 32 * 8];      // transpose tile 2 KB
    __shared__ __align__(16) char lds_pad[8192];       // >80KB total => 1 WG/CU guaranteed

    const int bid  = blockIdx.x;
    const int g    = bid & 7;
    const int s    = bid >> 3;
    const int b0   = g * 32;
    const int tid  = threadIdx.x;
    const int p    = tid >> 6;
    const int lane = tid & 63;
    const int l31  = lane & 31;
    const int kg   = lane >> 5;
    const int lo   = kg * 256 + l31 * 8;

    if (tid == 255) *(volatile char*)lds_pad = 0;      // keep pad allocated

    u32* gslots = bar + g * 64;
    u16* Xdg = Xd + (size_t)g * 7168;

    // K-split: waves cover k-tiles [ktb, ktb+ktc); padded to uniform 20 via zero-B
    const int ktb = p * 20 - (p == 3 ? 1 : 0);
    const int ktc = (p < 2) ? 20 : 19;

    // ---- pin B for all 4 gates, this wave's k-range (pad tiles zeroed) ----
    short8 Bfrag[4][20];
#pragma unroll
    for (int gg = 0; gg < 4; ++gg) {
        const u16* pw = Wcat + (size_t)(gg * 1024 + s * 32 + l31) * KA + kg * 8;
#pragma unroll
        for (int j = 0; j < 20; ++j) {
            if (j < ktc) {
                int kt = ktb + j;
                Bfrag[gg][j] = *(const short8*)(pw + (size_t)kt * 16);
            } else {
                Bfrag[gg][j] = short8{};
            }
        }
    }

    // pointwise mapping: thread -> (col cs, 4 batches bq*4..)
    const int cs = tid & 31;
    const int bq = tid >> 5;
    float creg[4] = {0.f, 0.f, 0.f, 0.f};
    const int hcg = s * 32 + cs;
    const float bI  = b_ih[hcg]        + b_hh[hcg];
    const float bF  = b_ih[1024 + hcg] + b_hh[1024 + hcg];
    const float bG_ = b_ih[2048 + hcg] + b_hh[2048 + hcg];
    const float bO  = b_ih[3072 + hcg] + b_hh[3072 + hcg];
    const float bOutv = (s < 7 && hcg < OUTD) ? b_out[hcg] : 0.f;

    for (int t = 0; t < NSTEP; ++t) {
        const u16* hb    = H + (size_t)(t & 1) * (MB * HDIM) + (size_t)g * 32768;  // h_t
        u16*       HTn   = H + (size_t)((t + 1) & 1) * (MB * HDIM);
        const u16* hnext = HTn + (size_t)g * 32768;                                // h_{t+1}
        const u16* xb;
        if (t < SRCT)       xb = srcbf + (size_t)(t * 8 + g) * 7168;
        else if (t == SRCT) xb = srcbf + (size_t)((SRCT - 1) * 8 + g) * 7168;
        else                xb = Xdg;

        // ---- gate GEMM: pipelined direct loads feeding pinned-B MFMAs ----
        f32x16 acc[4] = {f32x16{}, f32x16{}, f32x16{}, f32x16{}};
        {
            short8 av[20];
            gate_pro<0>(av, xb, hb, ktb, lo);
            gate_body<0>(av, Bfrag, acc, xb, hb, ktb, lo);
        }
#pragma unroll
        for (int gg = 0; gg < 4; ++gg) {
#pragma unroll
            for (int rq = 0; rq < 4; ++rq) {
                f32x4 v;
                v[0] = acc[gg][rq * 4 + 0]; v[1] = acc[gg][rq * 4 + 1];
                v[2] = acc[gg][rq * 4 + 2]; v[3] = acc[gg][rq * 4 + 3];
                *(f32x4*)&G2[(size_t)((gg * 4 + p) * 32 + l31) * 36 + rq * 8 + kg * 4] = v;
            }
        }
        __syncthreads();

        // ---- pointwise cell ----
        {
            f32x4 sg[4];
#pragma unroll
            for (int gg = 0; gg < 4; ++gg) {
                f32x4 a = *(const f32x4*)&G2[(size_t)((gg * 4 + 0) * 32 + cs) * 36 + bq * 4];
#pragma unroll
                for (int pp = 1; pp < 4; ++pp)
                    a += *(const f32x4*)&G2[(size_t)((gg * 4 + pp) * 32 + cs) * 36 + bq * 4];
                sg[gg] = a;
            }
#pragma unroll
            for (int i = 0; i < 4; ++i) {
                float gi = sg[0][i] + bI, gf = sg[1][i] + bF;
                float gG = sg[2][i] + bG_, go = sg[3][i] + bO;
                float c = sigm(gf) * creg[i] + sigm(gi) * tanh_(gG);
                creg[i] = c;
                Hx[(cs >> 3) * 256 + (bq * 4 + i) * 8 + (cs & 7)] = f2bf(sigm(go) * tanh_(c));
            }
        }
        __syncthreads();
        // coalesced write-through of this WG's h slice
        astore((u64*)HTn + (size_t)g * 8192 + s * 256 + tid, ((const u64*)Hx)[tid]);

        if (t < SRCT) {
            g_arrive(gslots, t);
            g_wait(gslots, t);
        } else {
            const int d  = t - SRCT;
            const int k1 = SRCT + 2 * d;
            g_arrive(gslots, k1);
            g_wait(gslots, k1);
            // out-GEMM (s<7): out = h_new @ Wo^T, h_new direct-loaded (post-barrier)
            if (s < 7) {
                f32x16 oacc = {};
                const int orow = (s * 32 + l31 < OUTD) ? (s * 32 + l31) : (OUTD - 1);
                const u16* wob = Wo + (size_t)orow * HDIM + kg * 8;
                short8 av2[16];
                out_pro<0>(av2, hnext, p * 16, lo);
                out_body<0>(av2, oacc, hnext, wob, p * 16, lo);
#pragma unroll
                for (int rq = 0; rq < 4; ++rq) {
                    f32x4 v;
                    v[0] = oacc[rq * 4 + 0]; v[1] = oacc[rq * 4 + 1];
                    v[2] = oacc[rq * 4 + 2]; v[3] = oacc[rq * 4 + 3];
                    *(f32x4*)&G2[(size_t)(p * 32 + l31) * 36 + rq * 8 + kg * 4] = v;
                }
            }
            __syncthreads();
            if (s < 7) {
                const int  ocol = s * 32 + cs;
                const bool real = ocol < OUTD;
                f32x4 S = *(const f32x4*)&G2[(size_t)(0 * 32 + cs) * 36 + bq * 4];
#pragma unroll
                for (int pp = 1; pp < 4; ++pp)
                    S += *(const f32x4*)&G2[(size_t)(pp * 32 + cs) * 36 + bq * 4];
#pragma unroll
                for (int i = 0; i < 4; ++i) {
                    float v = real ? (S[i] + bOutv) : 0.f;
                    Hx[(cs >> 3) * 256 + (bq * 4 + i) * 8 + (cs & 7)] = real ? f2bf(v) : (u16)0;
                    if (real)
                        dout[(size_t)(b0 + bq * 4 + i) * (DECT * OUTD) + (size_t)d * OUTD + ocol] = v;
                }
            }
            __syncthreads();
            if (s < 7)
                astore((u64*)Xdg + s * 256 + tid, ((const u64*)Hx)[tid]);
            if (t < NSTEP - 1) {
                g_arrive(gslots, k1 + 1);
                g_wait(gslots, k1 + 1);
            }
        }
    }
}

extern "C" void kernel_launch(void* const* d_in, const int* in_sizes, int n_in,
                              void* d_out, int out_size, void* d_ws, size_t ws_size,
                              hipStream_t stream) {
    const float* src   = (const float*)d_in[0];
    // d_in[1] = tgt (unused in eval forward)
    const float* W_ih  = (const float*)d_in[2];
    const float* W_hh  = (const float*)d_in[3];
    const float* b_ih  = (const float*)d_in[4];
    const float* b_hh  = (const float*)d_in[5];
    const float* W_out = (const float*)d_in[6];
    const float* b_out = (const float*)d_in[7];
    float* out = (float*)d_out;

    char* ws = (char*)d_ws;
    u16* srcbf = (u16*)(ws + OFF_SRCBF);
    u16* H     = (u16*)(ws + OFF_H);
    u16* Xd    = (u16*)(ws + OFF_XDEC);
    u16* Wcat  = (u16*)(ws + OFF_WCAT);
    u16* Wo    = (u16*)(ws + OFF_WO);
    u32* bar   = (u32*)(ws + OFF_BAR);

    hipLaunchKernelGGL(prep_kernel, dim3(2048), dim3(256), 0, stream,
                       src, W_ih, W_hh, W_out, srcbf, H, Xd, Wcat, Wo, bar);

    hipLaunchKernelGGL(lstm_persist, dim3(NWG), dim3(256), 0, stream,
                       srcbf, H, Xd, Wcat, Wo, b_ih, b_hh, b_out, out, bar);
}

// Round 2
// 860.340 us; speedup vs baseline: 1.1024x; 1.0100x over previous
//
#include <hip/hip_runtime.h>
#include <hip/hip_bf16.h>

typedef unsigned short u16;
typedef unsigned int   u32;
typedef unsigned long long u64;
typedef __attribute__((ext_vector_type(4)))  float  f32x4;
typedef __attribute__((ext_vector_type(8)))  short  short8;
typedef __attribute__((ext_vector_type(16))) float  f32x16;

#define MB     256
#define SRCT   120
#define DECT   24
#define NSTEP  144
#define DIN    216
#define HDIM   1024
#define KXP    224
#define KA     1248
#define NGATE  4096
#define OUTD   216
#define NWG    256

// ---- ws layout (bytes) ---- (unchanged)
#define OFF_SRCBF 0u
#define OFF_H     13762560u
#define OFF_XDEC  14811136u
#define OFF_WCAT  14925824u
#define OFF_WO    25149440u
#define OFF_BAR   25591808u      // 8 groups x 64 u32 (accumulating counters)

__device__ __forceinline__ u16 f2bf(float f) {
    union { float f; unsigned v; } c; c.f = f;
    return (u16)((c.v + 0x7FFFu + ((c.v >> 16) & 1u)) >> 16);
}
__device__ __forceinline__ float sigm(float x)  { return 1.0f / (1.0f + __expf(-x)); }
__device__ __forceinline__ float tanh_(float x) { return 1.0f - 2.0f / (1.0f + __expf(2.0f * x)); }

// plain write-back store: lands in the LOCAL XCD L2 (group == XCD, so all
// consumers share this L2). vmcnt(0) inside g_arrive's __syncthreads = L2 ack.
__device__ __forceinline__ void pstore(u64* p, u64 v) { *p = v; }

// L2-coherent 16B load: sc0 bypasses L1 (stale across the 2-step buffer reuse)
// but hits the XCD-local L2 where the group's producers wrote.
__device__ __forceinline__ short8 ld_l2(const u16* p) {
    short8 r;
    asm volatile("global_load_dwordx4 %0, %1, off sc0" : "=v"(r) : "v"(p));
    return r;
}
template <int N>
__device__ __forceinline__ void vwait() {
    asm volatile("s_waitcnt vmcnt(%0)" :: "n"(N));
    __builtin_amdgcn_sched_barrier(0);   // keep MFMAs from hoisting above the wait
}

// ---- single-counter group barrier (IC-based, proven): 1 atomicAdd / WG ----
__device__ __forceinline__ void g_arrive(u32* slots, int k) {
    __syncthreads();   // drains all waves' stores (vmcnt 0) before the flag
    if (threadIdx.x == 0) {
        asm volatile("s_waitcnt vmcnt(0)" ::: "memory");
        __hip_atomic_fetch_add(slots + (k & 63), 1u, __ATOMIC_RELAXED, __HIP_MEMORY_SCOPE_AGENT);
    }
}
__device__ __forceinline__ void g_wait(u32* slots, int k) {
    if (threadIdx.x == 0) {
        const u32 tgt = 32u * (u32)((k >> 6) + 1);
        while (__hip_atomic_load(slots + (k & 63), __ATOMIC_RELAXED, __HIP_MEMORY_SCOPE_AGENT) < tgt)
            __builtin_amdgcn_s_sleep(1);
    }
    __syncthreads();
}

// ---------------- prep: fp32 -> bf16, transposed comm layouts ----------------
__global__ void prep_kernel(const float* __restrict__ src,
                            const float* __restrict__ W_ih,
                            const float* __restrict__ W_hh,
                            const float* __restrict__ W_out,
                            u16* __restrict__ srcbf, u16* __restrict__ H,
                            u16* __restrict__ Xd,    u16* __restrict__ Wcat,
                            u16* __restrict__ Wo,    u32* __restrict__ bar) {
    const int nS  = SRCT * 8 * 28 * 256;
    const int nW  = NGATE * KA;
    const int nWo = OUTD * HDIM;
    const int nH  = MB * HDIM;
    const int nXd = 8 * 28 * 256;
    const int nB  = 8 * 64;
    const int total = nS + nW + nWo + nH + nXd + nB;
    for (int i = blockIdx.x * blockDim.x + threadIdx.x; i < total; i += gridDim.x * blockDim.x) {
        if (i < nS) {
            int r = i & 255, i2 = i >> 8;
            int m = r >> 3, e = r & 7;
            int oct = i2 % 28, q = i2 / 28;
            int gi = q & 7, t = q >> 3;
            int col = oct * 8 + e, b = gi * 32 + m;
            srcbf[i] = (col < DIN) ? f2bf(src[((size_t)b * SRCT + t) * DIN + col]) : (u16)0;
        } else if (i < nS + nW) {
            int j = i - nS;
            int r = j / KA, col = j % KA;
            u16 v = 0;
            if (col < DIN)       v = f2bf(W_ih[(size_t)r * DIN + col]);
            else if (col >= KXP) v = f2bf(W_hh[(size_t)r * HDIM + (col - KXP)]);
            Wcat[j] = v;
        } else if (i < nS + nW + nWo) {
            int j = i - nS - nW;
            Wo[j] = f2bf(W_out[j]);
        } else if (i < nS + nW + nWo + nH) {
            H[i - nS - nW - nWo] = 0;
        } else if (i < nS + nW + nWo + nH + nXd) {
            Xd[i - nS - nW - nWo - nH] = 0;   // also zeroes the 8 claim counters
        } else {
            bar[i - nS - nW - nWo - nH - nXd] = 0;
        }
    }
}

// ---------------- gate GEMM: direct-load A-fragment pipeline ----------------
template <int J>
__device__ __forceinline__ void gate_issue(short8 (&av)[20], const u16* xb, const u16* hb,
                                           int ktb, int lo) {
    int kt = ktb + J;
    if (kt > 77) kt = 77;                       // pad tile: valid addr, B is zeroed
    const int o2 = 2 * kt;
    const u16* base = (o2 < 28) ? (xb + o2 * 256) : (hb + (o2 - 28) * 256);
    av[J] = ld_l2(base + lo);
}
template <int J>
__device__ __forceinline__ void gate_pro(short8 (&av)[20], const u16* xb, const u16* hb,
                                         int ktb, int lo) {
    gate_issue<J>(av, xb, hb, ktb, lo);
    if constexpr (J + 1 < 8) gate_pro<J + 1>(av, xb, hb, ktb, lo);
}
template <int J>
__device__ __forceinline__ void gate_body(short8 (&av)[20], short8 (&Bf)[4][20], f32x16 (&acc)[4],
                                          const u16* xb, const u16* hb, int ktb, int lo) {
    if constexpr (J + 8 < 20) gate_issue<J + 8>(av, xb, hb, ktb, lo);
    vwait<(J + 8 < 20) ? 8 : (19 - J)>();
    acc[0] = __builtin_amdgcn_mfma_f32_32x32x16_bf16(av[J], Bf[0][J], acc[0], 0, 0, 0);
    acc[1] = __builtin_amdgcn_mfma_f32_32x32x16_bf16(av[J], Bf[1][J], acc[1], 0, 0, 0);
    acc[2] = __builtin_amdgcn_mfma_f32_32x32x16_bf16(av[J], Bf[2][J], acc[2], 0, 0, 0);
    acc[3] = __builtin_amdgcn_mfma_f32_32x32x16_bf16(av[J], Bf[3][J], acc[3], 0, 0, 0);
    if constexpr (J + 1 < 20) gate_body<J + 1>(av, Bf, acc, xb, hb, ktb, lo);
}

// ---------------- out GEMM: direct-load A (h_new), B from Wo ----------------
template <int J>
__device__ __forceinline__ void out_issue(short8 (&av)[16], const u16* hb, int kt0, int lo) {
    const int o2 = 2 * (kt0 + J);
    av[J] = ld_l2(hb + o2 * 256 + lo);
}
template <int J>
__device__ __forceinline__ void out_pro(short8 (&av)[16], const u16* hb, int kt0, int lo) {
    out_issue<J>(av, hb, kt0, lo);
    if constexpr (J + 1 < 8) out_pro<J + 1>(av, hb, kt0, lo);
}
template <int J>
__device__ __forceinline__ void out_body(short8 (&av)[16], f32x16& oacc, const u16* hb,
                                         const u16* wob, int kt0, int lo) {
    if constexpr (J + 8 < 16) out_issue<J + 8>(av, hb, kt0, lo);
    vwait<(J + 8 < 16) ? 8 : (15 - J)>();
    short8 bf = *(const short8*)(wob + (size_t)(kt0 + J) * 16);
    oacc = __builtin_amdgcn_mfma_f32_32x32x16_bf16(av[J], bf, oacc, 0, 0, 0);
    if constexpr (J + 1 < 16) out_body<J + 1>(av, oacc, hb, wob, kt0, lo);
}

// ---------------- persistent LSTM ----------------
// group g = XCD id (discovered via HW_REG_XCC_ID): batches [g*32,+32).
// slice s = per-XCD claim index (0..31): h-cols [s*32,+32) x 4 gates.
// 256 WGs, 1/CU (LDS-forced) => exactly 32 WGs per XCD => all group traffic
// (h, x-dec) is intra-XCD: plain write-back stores + sc0 loads through local L2.
__global__ void __launch_bounds__(256, 1)
lstm_persist(const u16* __restrict__ srcbf, u16* __restrict__ H,
             u16* __restrict__ Xd, const u16* __restrict__ Wcat,
             const u16* __restrict__ Wo,
             const float* __restrict__ b_ih, const float* __restrict__ b_hh,
             const float* __restrict__ b_out,
             float* __restrict__ dout, u32* __restrict__ bar)
{
    __shared__ __align__(16) float G2[16 * 32 * 36];   // [slab][col][b36] 73,728 B
    __shared__ __align__(16) u16  Hx[4 * 32 * 8];      // transpose tile 2 KB
    __shared__ __align__(16) char lds_pad[8192];       // >80KB total => 1 WG/CU guaranteed
    __shared__ int gs_share[2];

    const int tid  = threadIdx.x;
    const int p    = tid >> 6;
    const int lane = tid & 63;
    const int l31  = lane & 31;
    const int kg   = lane >> 5;
    const int lo   = kg * 256 + l31 * 8;

    if (tid == 255) *(volatile char*)lds_pad = 0;      // keep pad allocated

    // ---- XCD discovery + slice claim (claim counters live in Xd[0..7],
    // zeroed by prep; Xd proper is fully rewritten before its first read) ----
    if (tid == 0) {
        u32 xcc;
        asm volatile("s_getreg_b32 %0, hwreg(HW_REG_XCC_ID)" : "=s"(xcc));
        u32 myidx = __hip_atomic_fetch_add((u32*)Xd + xcc, 1u,
                                           __ATOMIC_RELAXED, __HIP_MEMORY_SCOPE_AGENT);
        gs_share[0] = (int)xcc;
        gs_share[1] = (int)myidx;
    }
    __syncthreads();
    const int g  = gs_share[0];
    const int s  = gs_share[1];
    const int b0 = g * 32;

    u32* gslots = bar + g * 64;
    u16* Xdg = Xd + (size_t)g * 7168;

    // K-split: waves cover k-tiles [ktb, ktb+ktc); padded to uniform 20 via zero-B
    const int ktb = p * 20 - (p == 3 ? 1 : 0);
    const int ktc = (p < 2) ? 20 : 19;

    // ---- pin B for all 4 gates, this wave's k-range (pad tiles zeroed) ----
    short8 Bfrag[4][20];
#pragma unroll
    for (int gg = 0; gg < 4; ++gg) {
        const u16* pw = Wcat + (size_t)(gg * 1024 + s * 32 + l31) * KA + kg * 8;
#pragma unroll
        for (int j = 0; j < 20; ++j) {
            if (j < ktc) {
                int kt = ktb + j;
                Bfrag[gg][j] = *(const short8*)(pw + (size_t)kt * 16);
            } else {
                Bfrag[gg][j] = short8{};
            }
        }
    }

    // pointwise mapping: thread -> (col cs, 4 batches bq*4..)
    const int cs = tid & 31;
    const int bq = tid >> 5;
    float creg[4] = {0.f, 0.f, 0.f, 0.f};
    const int hcg = s * 32 + cs;
    const float bI  = b_ih[hcg]        + b_hh[hcg];
    const float bF  = b_ih[1024 + hcg] + b_hh[1024 + hcg];
    const float bG_ = b_ih[2048 + hcg] + b_hh[2048 + hcg];
    const float bO  = b_ih[3072 + hcg] + b_hh[3072 + hcg];
    const float bOutv = (s < 7 && hcg < OUTD) ? b_out[hcg] : 0.f;

    for (int t = 0; t < NSTEP; ++t) {
        const u16* hb    = H + (size_t)(t & 1) * (MB * HDIM) + (size_t)g * 32768;  // h_t
        u16*       HTn   = H + (size_t)((t + 1) & 1) * (MB * HDIM);
        const u16* hnext = HTn + (size_t)g * 32768;                                // h_{t+1}
        const u16* xb;
        if (t < SRCT)       xb = srcbf + (size_t)(t * 8 + g) * 7168;
        else if (t == SRCT) xb = srcbf + (size_t)((SRCT - 1) * 8 + g) * 7168;
        else                xb = Xdg;

        // ---- gate GEMM: pipelined L2 loads feeding pinned-B MFMAs ----
        f32x16 acc[4] = {f32x16{}, f32x16{}, f32x16{}, f32x16{}};
        {
            short8 av[20];
            gate_pro<0>(av, xb, hb, ktb, lo);
            gate_body<0>(av, Bfrag, acc, xb, hb, ktb, lo);
        }
#pragma unroll
        for (int gg = 0; gg < 4; ++gg) {
#pragma unroll
            for (int rq = 0; rq < 4; ++rq) {
                f32x4 v;
                v[0] = acc[gg][rq * 4 + 0]; v[1] = acc[gg][rq * 4 + 1];
                v[2] = acc[gg][rq * 4 + 2]; v[3] = acc[gg][rq * 4 + 3];
                *(f32x4*)&G2[(size_t)((gg * 4 + p) * 32 + l31) * 36 + rq * 8 + kg * 4] = v;
            }
        }
        __syncthreads();

        // ---- pointwise cell ----
        {
            f32x4 sg[4];
#pragma unroll
            for (int gg = 0; gg < 4; ++gg) {
                f32x4 a = *(const f32x4*)&G2[(size_t)((gg * 4 + 0) * 32 + cs) * 36 + bq * 4];
#pragma unroll
                for (int pp = 1; pp < 4; ++pp)
                    a += *(const f32x4*)&G2[(size_t)((gg * 4 + pp) * 32 + cs) * 36 + bq * 4];
                sg[gg] = a;
            }
#pragma unroll
            for (int i = 0; i < 4; ++i) {
                float gi = sg[0][i] + bI, gf = sg[1][i] + bF;
                float gG = sg[2][i] + bG_, go = sg[3][i] + bO;
                float c = sigm(gf) * creg[i] + sigm(gi) * tanh_(gG);
                creg[i] = c;
                Hx[(cs >> 3) * 256 + (bq * 4 + i) * 8 + (cs & 7)] = f2bf(sigm(go) * tanh_(c));
            }
        }
        __syncthreads();
        // coalesced write-through of this WG's h slice into the LOCAL L2
        pstore((u64*)HTn + (size_t)g * 8192 + s * 256 + tid, ((const u64*)Hx)[tid]);

        if (t < SRCT) {
            g_arrive(gslots, t);
            g_wait(gslots, t);
        } else {
            const int d  = t - SRCT;
            const int k1 = SRCT + 2 * d;
            g_arrive(gslots, k1);
            g_wait(gslots, k1);
            // out-GEMM (s<7): out = h_new @ Wo^T, h_new from local L2 (post-barrier)
            if (s < 7) {
                f32x16 oacc = {};
                const int orow = (s * 32 + l31 < OUTD) ? (s * 32 + l31) : (OUTD - 1);
                const u16* wob = Wo + (size_t)orow * HDIM + kg * 8;
                short8 av2[16];
                out_pro<0>(av2, hnext, p * 16, lo);
                out_body<0>(av2, oacc, hnext, wob, p * 16, lo);
#pragma unroll
                for (int rq = 0; rq < 4; ++rq) {
                    f32x4 v;
                    v[0] = oacc[rq * 4 + 0]; v[1] = oacc[rq * 4 + 1];
                    v[2] = oacc[rq * 4 + 2]; v[3] = oacc[rq * 4 + 3];
                    *(f32x4*)&G2[(size_t)(p * 32 + l31) * 36 + rq * 8 + kg * 4] = v;
                }
            }
            __syncthreads();
            if (s < 7) {
                const int  ocol = s * 32 + cs;
                const bool real = ocol < OUTD;
                f32x4 S = *(const f32x4*)&G2[(size_t)(0 * 32 + cs) * 36 + bq * 4];
#pragma unroll
                for (int pp = 1; pp < 4; ++pp)
                    S += *(const f32x4*)&G2[(size_t)(pp * 32 + cs) * 36 + bq * 4];
#pragma unroll
                for (int i = 0; i < 4; ++i) {
                    float v = real ? (S[i] + bOutv) : 0.f;
                    Hx[(cs >> 3) * 256 + (bq * 4 + i) * 8 + (cs & 7)] = real ? f2bf(v) : (u16)0;
                    if (real)
                        dout[(size_t)(b0 + bq * 4 + i) * (DECT * OUTD) + (size_t)d * OUTD + ocol] = v;
                }
            }
            __syncthreads();
            if (s < 7)
                pstore((u64*)Xdg + s * 256 + tid, ((const u64*)Hx)[tid]);
            if (t < NSTEP - 1) {
                g_arrive(gslots, k1 + 1);
                g_wait(gslots, k1 + 1);
            }
        }
    }
}

extern "C" void kernel_launch(void* const* d_in, const int* in_sizes, int n_in,
                              void* d_out, int out_size, void* d_ws, size_t ws_size,
                              hipStream_t stream) {
    const float* src   = (const float*)d_in[0];
    // d_in[1] = tgt (unused in eval forward)
    const float* W_ih  = (const float*)d_in[2];
    const float* W_hh  = (const float*)d_in[3];
    const float* b_ih  = (const float*)d_in[4];
    const float* b_hh  = (const float*)d_in[5];
    const float* W_out = (const float*)d_in[6];
    const float* b_out = (const float*)d_in[7];
    float* out = (float*)d_out;

    char* ws = (char*)d_ws;
    u16* srcbf = (u16*)(ws + OFF_SRCBF);
    u16* H     = (u16*)(ws + OFF_H);
    u16* Xd    = (u16*)(ws + OFF_XDEC);
    u16* Wcat  = (u16*)(ws + OFF_WCAT);
    u16* Wo    = (u16*)(ws + OFF_WO);
    u32* bar   = (u32*)(ws + OFF_BAR);

    hipLaunchKernelGGL(prep_kernel, dim3(2048), dim3(256), 0, stream,
                       src, W_ih, W_hh, W_out, srcbf, H, Xd, Wcat, Wo, bar);

    hipLaunchKernelGGL(lstm_persist, dim3(NWG), dim3(256), 0, stream,
                       srcbf, H, Xd, Wcat, Wo, b_ih, b_hh, b_out, out, bar);
}